// Round 14
// baseline (296.083 us; speedup 1.0000x reference)
//
#include <hip/hip_runtime.h>
#include <hip/hip_bf16.h>
#include <stdint.h>

#define B_ROWS 16384
#define D_IN   512
#define H_DIM  1024
#define K_TOT  1536
#define NKT    48          // K-tiles of 32

typedef __attribute__((ext_vector_type(8)))  short bf16x8;
typedef __attribute__((ext_vector_type(4)))  float f32x4;
typedef __attribute__((ext_vector_type(4)))  float float4v;
typedef __attribute__((ext_vector_type(8)))  unsigned short u16x8;

__device__ __forceinline__ unsigned short f2bf(float f) {
    uint32_t u = __float_as_uint(f);
    u = (u + 0x7FFFu + ((u >> 16) & 1u)) >> 16;   // RNE
    return (unsigned short)u;
}

// ---------------------------------------------------------------------------
// Ag fragment-linear, 256-row tiles, BK=32 (unchanged from R13):
//   granule g = ((bm*48 + T)*16 + chunk)*64 + lane    (16 B)
//   lane l: row = bm*256 + chunk*16 + (l&15) ; k = T*32 + (l>>4)*8 + j
// ---------------------------------------------------------------------------
__global__ void cvt_A(const float* __restrict__ x, const float* __restrict__ h,
                      unsigned short* __restrict__ Ag) {
    int t     = blockIdx.x * blockDim.x + threadIdx.x;
    int lane  = t & 63;
    int chunk = (t >> 6) & 15;
    int rest  = t >> 10;            // bm*48 + T
    int T     = rest % 48;
    int bm    = rest / 48;
    int row   = bm * 256 + chunk * 16 + (lane & 15);
    int k     = T * 32 + (lane >> 4) * 8;
    const float* src = (k < 512) ? (x + (size_t)row * D_IN + k)
                                 : (h + (size_t)row * H_DIM + (k - 512));
    float4v v0 = *(const float4v*)(src);
    float4v v1 = *(const float4v*)(src + 4);
    u16x8 o;
    o[0] = f2bf(v0[0]); o[1] = f2bf(v0[1]); o[2] = f2bf(v0[2]); o[3] = f2bf(v0[3]);
    o[4] = f2bf(v1[0]); o[5] = f2bf(v1[1]); o[6] = f2bf(v1[2]); o[7] = f2bf(v1[3]);
    *(u16x8*)(Ag + (size_t)t * 8) = o;
}

// ---------------------------------------------------------------------------
// Bg fragment-linear, gate-interleaved cols (granularity 16, R1-proven):
//   col c = (h>>4)*64 + gate*16 + (h&15)
//   granule g = ((bn*48 + T)*16 + chunk)*64 + lane
// ---------------------------------------------------------------------------
__global__ void cvt_B(const float* __restrict__ Ui, const float* __restrict__ Uf,
                      const float* __restrict__ Uo, const float* __restrict__ Uc,
                      const float* __restrict__ Wi, const float* __restrict__ Wf,
                      const float* __restrict__ Wo, const float* __restrict__ Wc,
                      unsigned short* __restrict__ Bg) {
    int t     = blockIdx.x * blockDim.x + threadIdx.x;
    int lane  = t & 63;
    int chunk = (t >> 6) & 15;
    int rest  = t >> 10;            // bn*48 + T
    int T     = rest % 48;
    int bn    = rest / 48;
    int c     = bn * 256 + chunk * 16 + (lane & 15);
    int g     = (c >> 4) & 3;
    int hcol  = ((c >> 6) << 4) | (c & 15);
    int k     = T * 32 + (lane >> 4) * 8;
    const float* up = (g == 0) ? Ui : (g == 1) ? Uf : (g == 2) ? Uo : Uc;
    const float* wp = (g == 0) ? Wi : (g == 1) ? Wf : (g == 2) ? Wo : Wc;
    u16x8 o;
    if (k < 512) {
        const float* s = up + (size_t)k * H_DIM + hcol;
        #pragma unroll
        for (int i = 0; i < 8; ++i) o[i] = f2bf(s[(size_t)i * H_DIM]);
    } else {
        const float* s = wp + (size_t)(k - 512) * H_DIM + hcol;
        #pragma unroll
        for (int i = 0; i < 8; ++i) o[i] = f2bf(s[(size_t)i * H_DIM]);
    }
    *(u16x8*)(Bg + (size_t)t * 8) = o;
}

__global__ void cvt_bias(const float* __restrict__ Uib, const float* __restrict__ Ufb,
                         const float* __restrict__ Uob, const float* __restrict__ Ucb,
                         const float* __restrict__ Wib, const float* __restrict__ Wfb,
                         const float* __restrict__ Wob, const float* __restrict__ Wcb,
                         float* __restrict__ bias) {
    int t = blockIdx.x * blockDim.x + threadIdx.x;
    int g = t >> 10, h = t & 1023;
    const float* ub = (g == 0) ? Uib : (g == 1) ? Ufb : (g == 2) ? Uob : Ucb;
    const float* wb = (g == 0) ? Wib : (g == 1) ? Wfb : (g == 2) ? Wob : Wcb;
    bias[t] = ub[h] + wb[h];
}

// ---------------------------------------------------------------------------
// 256x256 GEMM, 16x16x32 MFMA, BK=32. SPLIT OPERAND STREAMS:
//   A: global -> VGPR direct (8 coalesced dwordx4/tile/wave, fragment-linear,
//      double-buffered 1 tile ahead; wm-sharing waves dedup in L1).  [VMEM pipe]
//   B: LDS ring-5 x 16 KiB (2 glds/tile/wave stage, 4 ds_read_b128/tile). [LDS pipe]
// Per tile t: { 4 ds_read B(t) ; 8 gload A(t+1) ; 2 glds stage B(t+3) ;
//              32 MFMA ; s_waitcnt vmcnt(2) ; s_barrier }.
// Gate drains A(t+1) + stage B(t+2), leaves stage B(t+3) in flight (never 0).
// RAW: B(t) staged at t-3, drained by t-2's gate -> resident 1 tile + barrier
// before read (ring-5 gives 1 extra tile of hoist margin). WAR: stage(t+3)
// targets slot (t-2)%5, last read 2 barriers prior. Tail wraps verified.
// LDS/tile/CU: 32K read + 16K write (~30% pipe) ; VMEM A 64K (L1-dedup'd) ;
// MFMA 1242 cyc -- three different pipes, each <= matrix budget.
// ---------------------------------------------------------------------------
__global__ __launch_bounds__(512) void lstm_gemm(
        const unsigned short* __restrict__ Ag, const unsigned short* __restrict__ Bg,
        const float* __restrict__ bias, const float* __restrict__ c_old,
        float* __restrict__ out) {
    __shared__ __align__(1024) char lds[81920];   // 5 slots x 16 KiB (B only)

    const int tid = threadIdx.x;
    const int l   = tid & 63;
    const int wv  = tid >> 6;
    const int wm  = wv >> 2;      // 0..1  (128-row slice)
    const int wn  = wv & 3;       // 0..3  (64-col slice)

    // XCD swizzle: per XCD 8bm x 4bn
    const int orig = blockIdx.x;              // 1024 blocks
    const int xcd  = orig & 7;
    const int jj   = orig >> 3;
    const int bn   = (xcd & 3) * 4 + (jj & 3);     // 0..15
    const int bm   = (xcd >> 2) * 32 + (jj >> 2);  // 0..63

    // A per-lane base: frag i of tile t at + t*8192 + i*512 elems
    const unsigned short* aBase =
        Ag + ((size_t)bm * 48 * 16 + wm * 8) * 512 + l * 8;
    // B stage source: chunks {2wv, 2wv+1} of tile t
    const unsigned short* bSrc =
        Bg + ((size_t)bn * 48 * 16 + 2 * wv) * 512 + l * 8;
    // B read offset in slot
    const int bRd = wn * 4096 + l * 16;            // + n*1024

#define GLDS(SRC, DST) __builtin_amdgcn_global_load_lds(                            \
        (const __attribute__((address_space(1))) void*)(SRC),                       \
        (__attribute__((address_space(3))) void*)(DST), 16, 0, 0)

#define STAGE_B(T, SLOTBASE) do {                                                   \
    const unsigned short* _s = bSrc + (size_t)(T) * 8192;                           \
    char* _d = (char*)lds + (SLOTBASE) + wv * 2048;                                 \
    GLDS(_s, _d);  GLDS(_s + 512, _d + 1024);                                       \
} while (0)

#define ALOAD(AF, T) do {                                                           \
    const unsigned short* _a = aBase + (size_t)(T) * 8192;                          \
    AF[0] = *(const u16x8*)(_a);        AF[1] = *(const u16x8*)(_a + 512);          \
    AF[2] = *(const u16x8*)(_a + 1024); AF[3] = *(const u16x8*)(_a + 1536);         \
    AF[4] = *(const u16x8*)(_a + 2048); AF[5] = *(const u16x8*)(_a + 2560);         \
    AF[6] = *(const u16x8*)(_a + 3072); AF[7] = *(const u16x8*)(_a + 3584);         \
} while (0)

    f32x4 acc[8][4] = {};

#define TILE(AC, AN, T, RD, SS) do {                                                \
    const char* _B = (const char*)lds + (RD) + bRd;                                 \
    bf16x8 bF[4];                                                                   \
    _Pragma("unroll") for (int n = 0; n < 4; ++n)                                   \
        bF[n] = *(const bf16x8*)(_B + n * 1024);                                    \
    int _tn = (T) + 1; if (_tn >= NKT) _tn = 0;      /* wrap: dummy, never used */  \
    ALOAD(AN, _tn);                                                                 \
    int _ts = (T) + 3; if (_ts >= NKT) _ts -= NKT;   /* wrap: staged, never read */ \
    STAGE_B(_ts, SS);                                                               \
    __builtin_amdgcn_s_setprio(1);                                                  \
    _Pragma("unroll") for (int i = 0; i < 8; ++i)                                   \
        _Pragma("unroll") for (int n = 0; n < 4; ++n)                               \
            acc[i][n] = __builtin_amdgcn_mfma_f32_16x16x32_bf16(                    \
                (bf16x8)AC[i], bF[n], acc[i][n], 0, 0, 0);                          \
    __builtin_amdgcn_s_setprio(0);                                                  \
    asm volatile("s_waitcnt vmcnt(2)");                                             \
    __builtin_amdgcn_s_barrier();                                                   \
} while (0)

    u16x8 aP[8], aQ[8];

    // ---- prologue: load A(0); stage B tiles 0,1,2 -> slots 0,1,2 ----
    ALOAD(aP, 0);
    STAGE_B(0, 0);
    STAGE_B(1, 16384);
    STAGE_B(2, 32768);
    asm volatile("s_waitcnt vmcnt(2)");   // A(0) + B(0),B(1) resident
    __builtin_amdgcn_s_barrier();

    int rdB = 0;        // (t%5)*16384
    int ssB = 49152;    // ((t+3)%5)*16384

    // ---- main loop: 24 iters x 2 tiles (A reg ping-pong, static idx) ----
    #pragma unroll 1
    for (int i = 0; i < 24; ++i) {
        const int t0 = 2 * i;
        TILE(aP, aQ, t0, rdB, ssB);
        rdB = (rdB == 65536) ? 0 : rdB + 16384;
        ssB = (ssB == 65536) ? 0 : ssB + 16384;
        TILE(aQ, aP, t0 + 1, rdB, ssB);
        rdB = (rdB == 65536) ? 0 : rdB + 16384;
        ssB = (ssB == 65536) ? 0 : ssB + 16384;
    }
    asm volatile("s_waitcnt vmcnt(0)");   // drain wrapped stagings/loads

    // ---- fused LSTM epilogue: gate = n (in-lane), hh = (bn*4+wn)*16 + col ----
    const int hh  = (bn * 4 + wn) * 16 + (l & 15);
    const float bi  = bias[hh];
    const float bff = bias[1024 + hh];
    const float bo  = bias[2048 + hh];
    const float bc  = bias[3072 + hh];

    #pragma unroll
    for (int a = 0; a < 8; ++a) {
        const int rb = bm * 256 + wm * 128 + a * 16 + ((l >> 4) * 4);
        #pragma unroll
        for (int j = 0; j < 4; ++j) {
            const int r = rb + j;
            float iv = acc[a][0][j] + bi;
            float fv = acc[a][1][j] + bff;
            float ov = acc[a][2][j] + bo;
            float gv = acc[a][3][j] + bc;
            float it = 1.f / (1.f + __expf(-iv));
            float ft = 1.f / (1.f + __expf(-fv));
            float ot = 1.f / (1.f + __expf(-ov));
            float gt = 1.f - 2.f / (1.f + __expf(2.f * gv));
            float co = c_old[(size_t)r * H_DIM + hh];
            float cn = it * gt + ft * co;
            float th = 1.f - 2.f / (1.f + __expf(2.f * cn));
            out[(size_t)r * H_DIM + hh] = ot * th;                          // h_new
            out[(size_t)B_ROWS * H_DIM + (size_t)r * H_DIM + hh] = cn;      // c
        }
    }
#undef TILE
#undef ALOAD
#undef STAGE_B
#undef GLDS
}

extern "C" void kernel_launch(void* const* d_in, const int* in_sizes, int n_in,
                              void* d_out, int out_size, void* d_ws, size_t ws_size,
                              hipStream_t stream) {
    const float* x  = (const float*)d_in[0];
    const float* h0 = (const float*)d_in[1];
    const float* c0 = (const float*)d_in[2];
    const float* Uw[4] = {(const float*)d_in[3],  (const float*)d_in[5],
                          (const float*)d_in[7],  (const float*)d_in[9]};
    const float* Ub[4] = {(const float*)d_in[4],  (const float*)d_in[6],
                          (const float*)d_in[8],  (const float*)d_in[10]};
    const float* Ww[4] = {(const float*)d_in[11], (const float*)d_in[13],
                          (const float*)d_in[15], (const float*)d_in[17]};
    const float* Wb[4] = {(const float*)d_in[12], (const float*)d_in[14],
                          (const float*)d_in[16], (const float*)d_in[18]};

    unsigned short* Ag = (unsigned short*)d_ws;                 // 48 MiB
    unsigned short* Bg = Ag + (size_t)B_ROWS * K_TOT;           // 12 MiB
    float* bias        = (float*)(Bg + (size_t)4096 * K_TOT);   // 16 KiB
    float* out         = (float*)d_out;

    cvt_A<<<12288, 256, 0, stream>>>(x, h0, Ag);
    cvt_B<<<3072, 256, 0, stream>>>(Uw[0], Uw[1], Uw[2], Uw[3],
                                    Ww[0], Ww[1], Ww[2], Ww[3], Bg);
    cvt_bias<<<16, 256, 0, stream>>>(Ub[0], Ub[1], Ub[2], Ub[3],
                                     Wb[0], Wb[1], Wb[2], Wb[3], bias);
    lstm_gemm<<<1024, 512, 0, stream>>>(Ag, Bg, bias, c0, out);
}